// Round 1
// baseline (557.419 us; speedup 1.0000x reference)
//
#include <hip/hip_runtime.h>
#include <hip/hip_bf16.h>
#include <math.h>

#define HIDDEN 2048
#define N_EXPERTS 5
#define TOP_K 2

// Wave-per-token MoE gate + fused token copy.
// block = 256 (4 waves), grid = 1024 -> 4 blocks/CU, LDS 40KB/block (4*40=160KB = full CU pool).
__global__ __launch_bounds__(256, 4)
void moe_gate_kernel(const float* __restrict__ x,      // [N, HIDDEN]
                     const float* __restrict__ W,      // [N_EXPERTS, HIDDEN]
                     float* __restrict__ out_w,        // [N, 2]
                     float* __restrict__ out_i,        // [N, 2] (indices as floats)
                     float* __restrict__ out_tok,      // [N, HIDDEN]
                     int n_tokens) {
    __shared__ float w_lds[N_EXPERTS * HIDDEN];  // 40 KB

    // Cooperative W load: 10240 floats = 2560 float4
    {
        const float4* Wv = (const float4*)W;
        float4* Lv = (float4*)w_lds;
        for (int i = threadIdx.x; i < (N_EXPERTS * HIDDEN) / 4; i += blockDim.x) {
            Lv[i] = Wv[i];
        }
    }
    __syncthreads();

    const int lane = threadIdx.x & 63;
    const int wave = threadIdx.x >> 6;
    const int waves_per_block = blockDim.x >> 6;
    const int global_wave = blockIdx.x * waves_per_block + wave;
    const int total_waves = gridDim.x * waves_per_block;

    const float4* w_lds_v = (const float4*)w_lds;

    for (int tok = global_wave; tok < n_tokens; tok += total_waves) {
        const float4* xp = (const float4*)(x + (size_t)tok * HIDDEN);
        float4* op = (float4*)(out_tok + (size_t)tok * HIDDEN);

        float acc0 = 0.f, acc1 = 0.f, acc2 = 0.f, acc3 = 0.f, acc4 = 0.f;

        #pragma unroll
        for (int j = 0; j < HIDDEN / 4 / 64; ++j) {   // 8 iterations
            const int idx = j * 64 + lane;            // float4 index, coalesced
            const float4 xv = xp[idx];
            op[idx] = xv;                             // fused tokens copy
            {
                const float4 wv = w_lds_v[0 * (HIDDEN / 4) + idx];
                acc0 += xv.x * wv.x + xv.y * wv.y + xv.z * wv.z + xv.w * wv.w;
            }
            {
                const float4 wv = w_lds_v[1 * (HIDDEN / 4) + idx];
                acc1 += xv.x * wv.x + xv.y * wv.y + xv.z * wv.z + xv.w * wv.w;
            }
            {
                const float4 wv = w_lds_v[2 * (HIDDEN / 4) + idx];
                acc2 += xv.x * wv.x + xv.y * wv.y + xv.z * wv.z + xv.w * wv.w;
            }
            {
                const float4 wv = w_lds_v[3 * (HIDDEN / 4) + idx];
                acc3 += xv.x * wv.x + xv.y * wv.y + xv.z * wv.z + xv.w * wv.w;
            }
            {
                const float4 wv = w_lds_v[4 * (HIDDEN / 4) + idx];
                acc4 += xv.x * wv.x + xv.y * wv.y + xv.z * wv.z + xv.w * wv.w;
            }
        }

        // Wave-wide butterfly reduction (64 lanes) for each expert logit
        float logits[N_EXPERTS] = {acc0, acc1, acc2, acc3, acc4};
        #pragma unroll
        for (int e = 0; e < N_EXPERTS; ++e) {
            float v = logits[e];
            #pragma unroll
            for (int off = 32; off > 0; off >>= 1) {
                v += __shfl_xor(v, off, 64);
            }
            logits[e] = v;
        }

        if (lane == 0) {
            // top-1: strict > keeps lowest index on ties (lax.top_k stable order)
            int i1 = 0;
            float m1 = logits[0];
            #pragma unroll
            for (int e = 1; e < N_EXPERTS; ++e) {
                if (logits[e] > m1) { m1 = logits[e]; i1 = e; }
            }
            // top-2: first (lowest-index) max among the rest
            int i2 = -1;
            float m2 = -INFINITY;
            #pragma unroll
            for (int e = 0; e < N_EXPERTS; ++e) {
                if (e != i1 && logits[e] > m2) { m2 = logits[e]; i2 = e; }
            }
            // normalized top-2 softmax weights: full softmax denom cancels
            const float r = expf(m2 - m1);          // <= 1
            const float inv = 1.0f / (1.0f + r);
            out_w[(size_t)tok * 2 + 0] = inv;
            out_w[(size_t)tok * 2 + 1] = r * inv;
            out_i[(size_t)tok * 2 + 0] = (float)i1;
            out_i[(size_t)tok * 2 + 1] = (float)i2;
        }
    }
}

extern "C" void kernel_launch(void* const* d_in, const int* in_sizes, int n_in,
                              void* d_out, int out_size, void* d_ws, size_t ws_size,
                              hipStream_t stream) {
    const float* x = (const float*)d_in[0];   // [8,4096,2048] fp32
    const float* W = (const float*)d_in[1];   // [5,2048] fp32

    const int n_tokens = in_sizes[0] / HIDDEN;              // 32768

    float* out = (float*)d_out;
    float* out_w   = out;                                    // [N,2]
    float* out_i   = out + (size_t)n_tokens * TOP_K;         // [N,2]
    float* out_tok = out + (size_t)n_tokens * TOP_K * 2;     // [N,HIDDEN]

    dim3 grid(1024);
    dim3 block(256);
    moe_gate_kernel<<<grid, block, 0, stream>>>(x, W, out_w, out_i, out_tok, n_tokens);
}